// Round 1
// baseline (7365.051 us; speedup 1.0000x reference)
//
#include <hip/hip_runtime.h>

typedef __attribute__((ext_vector_type(8))) short bf16x8;
typedef __attribute__((ext_vector_type(4))) float f32x4;

#define NWG 32

__device__ __forceinline__ unsigned short f2bf(float f) {
  union { float f; unsigned u; } v; v.f = f;
  unsigned r = v.u + 0x7FFFu + ((v.u >> 16) & 1u);
  return (unsigned short)(r >> 16);
}

__device__ __forceinline__ float fast_tanh(float x) {
  float ax = fminf(fabsf(x), 15.f);
  float e = __expf(2.f * ax);
  float t = (e - 1.f) / (e + 1.f);
  return copysignf(t, x);
}

// ---------- prep: fp32->bf16 weight convert, zero h state + barrier ----------
__global__ void prep_kernel(const float* __restrict__ inW,
                            const float* __restrict__ i2h,
                            const float* __restrict__ h2h,
                            unsigned short* __restrict__ WinB,
                            unsigned short* __restrict__ WiB,
                            unsigned short* __restrict__ WhB,
                            unsigned short* __restrict__ h0,
                            unsigned short* __restrict__ h1,
                            unsigned* __restrict__ bar) {
  int i = blockIdx.x * 256 + threadIdx.x;  // grid covers 524288 = L*H*H
  WiB[i] = f2bf(i2h[i]);
  WhB[i] = f2bf(h2h[i]);
  if (i < 131072) WinB[i] = f2bf(inW[i]);
  if (i < 65536) { h0[i] = 0; h1[i] = 0; }
  if (i < 2) bar[i] = 0;
}

// ---------- proj: xe[s][b][n] = x[b,s,:] . input_W[n,:] + input_b[n] (bf16 out) ----------
__global__ __launch_bounds__(256) void proj_kernel(const float* __restrict__ x,
                                                   const unsigned short* __restrict__ WinB,
                                                   const float* __restrict__ inb,
                                                   unsigned short* __restrict__ xe) {
  const int tid = threadIdx.x;
  const int ln = tid & 63, wv = tid >> 6;
  const int wid = blockIdx.x * 4 + wv;  // 0..65535 ; M-tiles 2048 x N-tiles 32
  const int mt = wid >> 5, nt = wid & 31;
  const int mrow = ln & 15, quad = ln >> 4, koff = quad * 8;
  const float* arow = x + (size_t)(mt * 16 + mrow) * 256 + koff;   // m = b*512+s
  const unsigned short* brow = WinB + (size_t)(nt * 16 + mrow) * 256 + koff;
  f32x4 acc = {0.f, 0.f, 0.f, 0.f};
#pragma unroll
  for (int kk = 0; kk < 8; ++kk) {
    const int ko = kk * 32;
    bf16x8 af;
#pragma unroll
    for (int j = 0; j < 8; ++j) af[j] = (short)f2bf(arow[ko + j]);
    bf16x8 bf = *(const bf16x8*)(brow + ko);
    acc = __builtin_amdgcn_mfma_f32_16x16x32_bf16(af, bf, acc, 0, 0, 0);
  }
  const int n = nt * 16 + mrow;
  const float bias = inb[n];
  const int m0 = mt * 16 + quad * 4;
#pragma unroll
  for (int r = 0; r < 4; ++r) {
    const int m = m0 + r;
    const int b = m >> 9, s = m & 511;
    xe[((size_t)(s * 64 + b) << 9) + n] = f2bf(acc[r] + bias);
  }
}

// ---------- persistent scan ----------
__device__ __forceinline__ void grid_barrier(unsigned* bar, unsigned epoch) {
  __syncthreads();
  if (threadIdx.x == 0) {
    __threadfence();  // release: waitcnt + buffer_wbl2 sc1 (cross-XCD writeback)
    unsigned prev = __hip_atomic_fetch_add(bar, 1u, __ATOMIC_RELAXED, __HIP_MEMORY_SCOPE_AGENT);
    if (prev == epoch * NWG + (NWG - 1)) {
      __hip_atomic_store(bar + 1, epoch + 1u, __ATOMIC_RELAXED, __HIP_MEMORY_SCOPE_AGENT);
    } else {
      while (__hip_atomic_load(bar + 1, __ATOMIC_RELAXED, __HIP_MEMORY_SCOPE_AGENT) < epoch + 1u) {
        __builtin_amdgcn_s_sleep(1);
      }
    }
    __threadfence();  // acquire: buffer_inv sc1 (invalidate stale L1/L2)
  }
  __syncthreads();
}

template <bool D0, bool D1>
__device__ __forceinline__ void stage_mfma(const unsigned short* __restrict__ aX,
                                           const unsigned short* __restrict__ aH0,
                                           const unsigned short* __restrict__ aH1,
                                           const bf16x8 (&wf)[4][16],
                                           f32x4& a0a, f32x4& a0b, f32x4& a1a, f32x4& a1b) {
#pragma unroll
  for (int kk = 0; kk < 16; ++kk) {
    const int ko = kk * 32;
    bf16x8 ah0 = *(const bf16x8*)(aH0 + ko);  // used by L0.h2h and L1.i2h
    if (D0) {
      bf16x8 ax = *(const bf16x8*)(aX + ko);
      a0a = __builtin_amdgcn_mfma_f32_16x16x32_bf16(ax, wf[0][kk], a0a, 0, 0, 0);
      a0b = __builtin_amdgcn_mfma_f32_16x16x32_bf16(ah0, wf[1][kk], a0b, 0, 0, 0);
    }
    if (D1) {
      a1a = __builtin_amdgcn_mfma_f32_16x16x32_bf16(ah0, wf[2][kk], a1a, 0, 0, 0);
      bf16x8 ah1 = *(const bf16x8*)(aH1 + ko);
      a1b = __builtin_amdgcn_mfma_f32_16x16x32_bf16(ah1, wf[3][kk], a1b, 0, 0, 0);
    }
  }
}

__global__ __launch_bounds__(256, 1) void scan_kernel(const unsigned short* __restrict__ xe,
                                                      const unsigned short* __restrict__ WiB,
                                                      const unsigned short* __restrict__ WhB,
                                                      const float* __restrict__ hb,
                                                      const float* __restrict__ outW,
                                                      const float* __restrict__ outb,
                                                      unsigned short* __restrict__ h0,
                                                      unsigned short* __restrict__ h1,
                                                      float* __restrict__ out,
                                                      unsigned* __restrict__ bar) {
  const int tid = threadIdx.x;
  const int ln = tid & 63, wv = tid >> 6;
  const int gw = blockIdx.x * 4 + wv;  // 0..127 waves
  const int mrow = ln & 15, quad = ln >> 4, koff = quad * 8;
  const int rt = gw & 3, ct = gw >> 2;  // row-tile (batch), col-tile (H)
  const int bA = rt * 16 + mrow;        // A fragment row = batch index
  const int n = ct * 16 + mrow;         // B fragment / output column

  // register-resident weights: rows n of Wi0, Wh0, Wi1, Wh1 (64 frags = 256 VGPR)
  bf16x8 wf[4][16];
  {
    const unsigned short* w0 = WiB + (size_t)n * 512 + koff;
    const unsigned short* w1 = WhB + (size_t)n * 512 + koff;
    const unsigned short* w2 = WiB + (size_t)(512 * 512) + (size_t)n * 512 + koff;
    const unsigned short* w3 = WhB + (size_t)(512 * 512) + (size_t)n * 512 + koff;
#pragma unroll
    for (int kk = 0; kk < 16; ++kk) {
      wf[0][kk] = *(const bf16x8*)(w0 + kk * 32);
      wf[1][kk] = *(const bf16x8*)(w1 + kk * 32);
      wf[2][kk] = *(const bf16x8*)(w2 + kk * 32);
      wf[3][kk] = *(const bf16x8*)(w3 + kk * 32);
    }
  }
  const float bias0 = hb[n], bias1 = hb[512 + n];
  const unsigned short* aXb = xe + (size_t)bA * 512 + koff;
  const unsigned short* h0b = h0 + (size_t)bA * 512 + koff;
  const unsigned short* h1b = h1 + (size_t)bA * 512 + koff;
  const int stc = (rt * 16 + quad * 4) * 512 + n;  // store base (C layout: row=quad*4+r, col=lane&15)

  // stage s: layer0 at t=s (s<512), layer1 at t=s-1 (s>=1). 513 stages, 513 barriers.
  for (int s = 0; s <= 512; ++s) {
    const int pd = s & 1, ps = pd ^ 1;
    f32x4 z = {0.f, 0.f, 0.f, 0.f};
    f32x4 a0a = z, a0b = z, a1a = z, a1b = z;
    const unsigned short* aX = aXb + ((size_t)s << 15);
    const unsigned short* aH0 = h0b + (ps << 15);  // h0(t-1) for L0.h2h == h0(s-1) for L1.i2h
    const unsigned short* aH1 = h1b + (pd << 15);  // h1(t-1) for L1.h2h
    if (s == 0)        stage_mfma<true, false>(aX, aH0, aH1, wf, a0a, a0b, a1a, a1b);
    else if (s == 512) stage_mfma<false, true>(aX, aH0, aH1, wf, a0a, a0b, a1a, a1b);
    else               stage_mfma<true, true>(aX, aH0, aH1, wf, a0a, a0b, a1a, a1b);

    if (s < 512) {  // layer0 output at t=s -> h0[pd]
      unsigned short* dst = h0 + (pd << 15) + stc;
      float* o = out + 16384 + stc;  // hT[0]
#pragma unroll
      for (int r = 0; r < 4; ++r) {
        float v = fast_tanh(a0a[r] + a0b[r] + bias0);
        dst[r << 9] = f2bf(v);
        if (s == 511) o[r << 9] = v;
      }
    }
    if (s > 0) {  // layer1 output at t=s-1 -> h1[ps]
      unsigned short* dst = h1 + (ps << 15) + stc;
      float* o = out + 16384 + 32768 + stc;  // hT[1]
#pragma unroll
      for (int r = 0; r < 4; ++r) {
        float v = fast_tanh(a1a[r] + a1b[r] + bias1);
        dst[r << 9] = f2bf(v);
        if (s == 512) o[r << 9] = v;
      }
    }
    grid_barrier(bar, (unsigned)s);
  }

  // output = hT[1] @ out_W.T + out_b, read from fp32 hT just written (barrier-ordered)
  const int g = blockIdx.x * 256 + tid;  // 0..8191
  const float* hT1 = out + 16384 + 32768;
#pragma unroll
  for (int e = 0; e < 2; ++e) {
    const int idx = g + e * 8192;  // 0..16383
    const int b = idx >> 8, o = idx & 255;
    const float* hr = hT1 + (b << 9);
    const float* wr = outW + (o << 9);
    float s0 = 0.f, s1 = 0.f;
    for (int k = 0; k < 512; k += 8) {
      float4 h4 = *(const float4*)(hr + k);
      float4 w4 = *(const float4*)(wr + k);
      s0 += h4.x * w4.x + h4.y * w4.y + h4.z * w4.z + h4.w * w4.w;
      float4 h5 = *(const float4*)(hr + k + 4);
      float4 w5 = *(const float4*)(wr + k + 4);
      s1 += h5.x * w5.x + h5.y * w5.y + h5.z * w5.z + h5.w * w5.w;
    }
    out[idx] = s0 + s1 + outb[o];
  }
}

extern "C" void kernel_launch(void* const* d_in, const int* in_sizes, int n_in,
                              void* d_out, int out_size, void* d_ws, size_t ws_size,
                              hipStream_t stream) {
  const float* x = (const float*)d_in[0];
  const float* inW = (const float*)d_in[1];
  const float* inb = (const float*)d_in[2];
  const float* i2h = (const float*)d_in[3];
  const float* h2h = (const float*)d_in[4];
  const float* hbias = (const float*)d_in[5];
  const float* outW = (const float*)d_in[6];
  const float* outb = (const float*)d_in[7];
  float* out = (float*)d_out;

  char* w = (char*)d_ws;
  unsigned short* WiB = (unsigned short*)w;                              // 1 MB
  unsigned short* WhB = (unsigned short*)(w + (1u << 20));               // 1 MB
  unsigned short* WinB = (unsigned short*)(w + (2u << 20));              // 256 KB
  unsigned short* h0 = (unsigned short*)(w + (2u << 20) + (256u << 10)); // 128 KB
  unsigned short* h1 = (unsigned short*)(w + (2u << 20) + (384u << 10)); // 128 KB
  unsigned* bar = (unsigned*)(w + (2u << 20) + (512u << 10));            // pad 1 KB
  unsigned short* xeB = (unsigned short*)(w + (2u << 20) + (512u << 10) + 1024);  // 32 MB

  prep_kernel<<<2048, 256, 0, stream>>>(inW, i2h, h2h, WinB, WiB, WhB, h0, h1, bar);
  proj_kernel<<<16384, 256, 0, stream>>>(x, WinB, inb, xeB);
  scan_kernel<<<NWG, 256, 0, stream>>>(xeB, WiB, WhB, hbias, outW, outb, h0, h1, out, bar);
}

// Round 2
// 6985.825 us; speedup vs baseline: 1.0543x; 1.0543x over previous
//
#include <hip/hip_runtime.h>

typedef __attribute__((ext_vector_type(8))) short bf16x8;
typedef __attribute__((ext_vector_type(4))) float f32x4;

#define NWG 32

__device__ __forceinline__ unsigned short f2bf(float f) {
  union { float f; unsigned u; } v; v.f = f;
  unsigned r = v.u + 0x7FFFu + ((v.u >> 16) & 1u);
  return (unsigned short)(r >> 16);
}

__device__ __forceinline__ float fast_tanh(float x) {
  float ax = fminf(fabsf(x), 15.f);
  float e = __expf(2.f * ax);
  float t = (e - 1.f) / (e + 1.f);
  return copysignf(t, x);
}

// L3-coherent (L2-bypass) 16B fragment load: two relaxed agent-scope 64-bit atomics.
__device__ __forceinline__ bf16x8 ldcoh(const unsigned short* p) {
  const unsigned long long* q = (const unsigned long long*)p;
  union { unsigned long long w[2]; bf16x8 v; } u;
  u.w[0] = __hip_atomic_load(q, __ATOMIC_RELAXED, __HIP_MEMORY_SCOPE_AGENT);
  u.w[1] = __hip_atomic_load(q + 1, __ATOMIC_RELAXED, __HIP_MEMORY_SCOPE_AGENT);
  return u.v;
}

// ---------- prep: fp32->bf16 weight convert, zero h state + barrier ----------
__global__ void prep_kernel(const float* __restrict__ inW,
                            const float* __restrict__ i2h,
                            const float* __restrict__ h2h,
                            unsigned short* __restrict__ WinB,
                            unsigned short* __restrict__ WiB,
                            unsigned short* __restrict__ WhB,
                            unsigned short* __restrict__ h0,
                            unsigned short* __restrict__ h1,
                            unsigned* __restrict__ bar) {
  int i = blockIdx.x * 256 + threadIdx.x;  // grid covers 524288 = L*H*H
  WiB[i] = f2bf(i2h[i]);
  WhB[i] = f2bf(h2h[i]);
  if (i < 131072) WinB[i] = f2bf(inW[i]);
  if (i < 65536) { h0[i] = 0; h1[i] = 0; }
  if (i < 2) bar[i] = 0;
}

// ---------- proj: xe[s][b][n] = x[b,s,:] . input_W[n,:] + input_b[n] (bf16 out) ----------
__global__ __launch_bounds__(256) void proj_kernel(const float* __restrict__ x,
                                                   const unsigned short* __restrict__ WinB,
                                                   const float* __restrict__ inb,
                                                   unsigned short* __restrict__ xe) {
  const int tid = threadIdx.x;
  const int ln = tid & 63, wv = tid >> 6;
  const int wid = blockIdx.x * 4 + wv;  // 0..65535 ; M-tiles 2048 x N-tiles 32
  const int mt = wid >> 5, nt = wid & 31;
  const int mrow = ln & 15, quad = ln >> 4, koff = quad * 8;
  const float* arow = x + (size_t)(mt * 16 + mrow) * 256 + koff;   // m = b*512+s
  const unsigned short* brow = WinB + (size_t)(nt * 16 + mrow) * 256 + koff;
  f32x4 acc = {0.f, 0.f, 0.f, 0.f};
#pragma unroll
  for (int kk = 0; kk < 8; ++kk) {
    const int ko = kk * 32;
    bf16x8 af;
#pragma unroll
    for (int j = 0; j < 8; ++j) af[j] = (short)f2bf(arow[ko + j]);
    bf16x8 bf = *(const bf16x8*)(brow + ko);
    acc = __builtin_amdgcn_mfma_f32_16x16x32_bf16(af, bf, acc, 0, 0, 0);
  }
  const int n = nt * 16 + mrow;
  const float bias = inb[n];
  const int m0 = mt * 16 + quad * 4;
#pragma unroll
  for (int r = 0; r < 4; ++r) {
    const int m = m0 + r;
    const int b = m >> 9, s = m & 511;
    xe[((size_t)(s * 64 + b) << 9) + n] = f2bf(acc[r] + bias);
  }
}

// ---------- grid barrier ----------
// FENCE=false: light — NO L2 writeback/invalidate. Safe because all cross-WG
// data (h0/h1) moves through sc1 (L2-bypass) atomic loads/stores, drained by
// s_waitcnt(0) before arrival. L2 stays warm for xe/weights.
// FENCE=true: full __threadfence protocol (used once, before the epilogue).
template <bool FENCE>
__device__ __forceinline__ void grid_barrier(unsigned* bar, unsigned epoch) {
  __builtin_amdgcn_s_waitcnt(0);  // each wave drains its own outstanding stores
  __syncthreads();
  if (threadIdx.x == 0) {
    if (FENCE) __threadfence();
    unsigned prev = __hip_atomic_fetch_add(bar, 1u, __ATOMIC_RELAXED, __HIP_MEMORY_SCOPE_AGENT);
    if (prev == epoch * NWG + (NWG - 1)) {
      __hip_atomic_store(bar + 1, epoch + 1u, __ATOMIC_RELAXED, __HIP_MEMORY_SCOPE_AGENT);
    } else {
      while (__hip_atomic_load(bar + 1, __ATOMIC_RELAXED, __HIP_MEMORY_SCOPE_AGENT) < epoch + 1u) {
        __builtin_amdgcn_s_sleep(1);
      }
    }
    if (FENCE) __threadfence();
  }
  __syncthreads();
}

template <bool D0, bool D1>
__device__ __forceinline__ void stage_mfma(const unsigned short* __restrict__ aX,
                                           const unsigned short* __restrict__ aH0,
                                           const unsigned short* __restrict__ aH1,
                                           const bf16x8 (&wf)[4][16],
                                           f32x4& a0a, f32x4& a0b, f32x4& a1a, f32x4& a1b) {
#pragma unroll
  for (int kk = 0; kk < 16; ++kk) {
    const int ko = kk * 32;
    bf16x8 ah0 = ldcoh(aH0 + ko);  // used by L0.h2h and L1.i2h
    if (D0) {
      bf16x8 ax = *(const bf16x8*)(aX + ko);  // normal load: read-only, L2-warm
      a0a = __builtin_amdgcn_mfma_f32_16x16x32_bf16(ax, wf[0][kk], a0a, 0, 0, 0);
      a0b = __builtin_amdgcn_mfma_f32_16x16x32_bf16(ah0, wf[1][kk], a0b, 0, 0, 0);
    }
    if (D1) {
      a1a = __builtin_amdgcn_mfma_f32_16x16x32_bf16(ah0, wf[2][kk], a1a, 0, 0, 0);
      bf16x8 ah1 = ldcoh(aH1 + ko);
      a1b = __builtin_amdgcn_mfma_f32_16x16x32_bf16(ah1, wf[3][kk], a1b, 0, 0, 0);
    }
  }
}

// Pack this lane's 4 tanh outputs (rows quad*4+0..3 of column n) with its
// column-neighbor via one shfl_xor, then store two dwords (two rows, column
// pair) with agent-scope relaxed atomics (sc1 -> L3-coherent, no fence needed).
__device__ __forceinline__ void store_h_coh(unsigned* dbase, int rowbase, int colp,
                                            bool evenl,
                                            float v0, float v1, float v2, float v3) {
  unsigned lo = (unsigned)f2bf(v0) | ((unsigned)f2bf(v1) << 16);
  unsigned hi = (unsigned)f2bf(v2) | ((unsigned)f2bf(v3) << 16);
  unsigned send = evenl ? hi : lo;
  unsigned recv = __shfl_xor(send, 1, 64);
  unsigned w0, w1; int rb;
  if (evenl) {  // rows rowbase+0, rowbase+1; low half = own col (even), high = partner (odd)
    w0 = (lo & 0xffffu) | (recv << 16);
    w1 = (lo >> 16) | (recv & 0xffff0000u);
    rb = rowbase;
  } else {      // rows rowbase+2, rowbase+3; low half = partner col (even), high = own (odd)
    w0 = (recv & 0xffffu) | (hi << 16);
    w1 = (recv >> 16) | (hi & 0xffff0000u);
    rb = rowbase + 2;
  }
  unsigned* p = dbase + rb * 256 + colp;
  __hip_atomic_store(p, w0, __ATOMIC_RELAXED, __HIP_MEMORY_SCOPE_AGENT);
  __hip_atomic_store(p + 256, w1, __ATOMIC_RELAXED, __HIP_MEMORY_SCOPE_AGENT);
}

__global__ __launch_bounds__(256, 1) void scan_kernel(const unsigned short* __restrict__ xe,
                                                      const unsigned short* __restrict__ WiB,
                                                      const unsigned short* __restrict__ WhB,
                                                      const float* __restrict__ hb,
                                                      const float* __restrict__ outW,
                                                      const float* __restrict__ outb,
                                                      unsigned short* __restrict__ h0,
                                                      unsigned short* __restrict__ h1,
                                                      float* __restrict__ out,
                                                      unsigned* __restrict__ bar) {
  const int tid = threadIdx.x;
  const int ln = tid & 63, wv = tid >> 6;
  const int gw = blockIdx.x * 4 + wv;  // 0..127 waves
  const int mrow = ln & 15, quad = ln >> 4, koff = quad * 8;
  const int rt = gw & 3, ct = gw >> 2;  // row-tile (batch), col-tile (H)
  const int bA = rt * 16 + mrow;        // A fragment row = batch index
  const int n = ct * 16 + mrow;         // B fragment / output column
  const bool evenl = (ln & 1) == 0;
  const int colp = n >> 1;
  const int rowbase = rt * 16 + quad * 4;

  // register-resident weights: rows n of Wi0, Wh0, Wi1, Wh1
  bf16x8 wf[4][16];
  {
    const unsigned short* w0 = WiB + (size_t)n * 512 + koff;
    const unsigned short* w1 = WhB + (size_t)n * 512 + koff;
    const unsigned short* w2 = WiB + (size_t)(512 * 512) + (size_t)n * 512 + koff;
    const unsigned short* w3 = WhB + (size_t)(512 * 512) + (size_t)n * 512 + koff;
#pragma unroll
    for (int kk = 0; kk < 16; ++kk) {
      wf[0][kk] = *(const bf16x8*)(w0 + kk * 32);
      wf[1][kk] = *(const bf16x8*)(w1 + kk * 32);
      wf[2][kk] = *(const bf16x8*)(w2 + kk * 32);
      wf[3][kk] = *(const bf16x8*)(w3 + kk * 32);
    }
  }
  const float bias0 = hb[n], bias1 = hb[512 + n];
  const unsigned short* aXb = xe + (size_t)bA * 512 + koff;
  const unsigned short* h0b = h0 + (size_t)bA * 512 + koff;
  const unsigned short* h1b = h1 + (size_t)bA * 512 + koff;

  // stage s: layer0 at t=s (s<512), layer1 at t=s-1 (s>=1). 513 stages/barriers.
  for (int s = 0; s <= 512; ++s) {
    const int pd = s & 1, ps = pd ^ 1;
    f32x4 z = {0.f, 0.f, 0.f, 0.f};
    f32x4 a0a = z, a0b = z, a1a = z, a1b = z;
    const unsigned short* aX = aXb + ((size_t)s << 15);
    const unsigned short* aH0 = h0b + (ps << 15);  // h0(s-1): L0.h2h input == L1.i2h input
    const unsigned short* aH1 = h1b + (pd << 15);  // h1(t-1) for L1.h2h
    if (s == 0)        stage_mfma<true, false>(aX, aH0, aH1, wf, a0a, a0b, a1a, a1b);
    else if (s == 512) stage_mfma<false, true>(aX, aH0, aH1, wf, a0a, a0b, a1a, a1b);
    else               stage_mfma<true, true>(aX, aH0, aH1, wf, a0a, a0b, a1a, a1b);

    if (s < 512) {  // layer0 output at t=s -> h0[pd]
      float v0 = fast_tanh(a0a[0] + a0b[0] + bias0);
      float v1 = fast_tanh(a0a[1] + a0b[1] + bias0);
      float v2 = fast_tanh(a0a[2] + a0b[2] + bias0);
      float v3 = fast_tanh(a0a[3] + a0b[3] + bias0);
      store_h_coh((unsigned*)h0 + (pd << 14), rowbase, colp, evenl, v0, v1, v2, v3);
      if (s == 511) {  // hT[0] (fp32, normal stores; flushed by the final fenced barrier)
        float* o = out + 16384 + rowbase * 512 + n;
        o[0] = v0; o[512] = v1; o[1024] = v2; o[1536] = v3;
      }
    }
    if (s > 0) {  // layer1 output at t=s-1 -> h1[ps]
      float v0 = fast_tanh(a1a[0] + a1b[0] + bias1);
      float v1 = fast_tanh(a1a[1] + a1b[1] + bias1);
      float v2 = fast_tanh(a1a[2] + a1b[2] + bias1);
      float v3 = fast_tanh(a1a[3] + a1b[3] + bias1);
      store_h_coh((unsigned*)h1 + (ps << 14), rowbase, colp, evenl, v0, v1, v2, v3);
      if (s == 512) {  // hT[1]
        float* o = out + 16384 + 32768 + rowbase * 512 + n;
        o[0] = v0; o[512] = v1; o[1024] = v2; o[1536] = v3;
      }
    }
    if (s == 512) grid_barrier<true>(bar, (unsigned)s);   // heavy: flush hT, drop stale lines
    else          grid_barrier<false>(bar, (unsigned)s);  // light: no L2 maintenance
  }

  // output = hT[1] @ out_W.T + out_b (normal loads: post-acquire-invalidate)
  const int g = blockIdx.x * 256 + tid;  // 0..8191
  const float* hT1 = out + 16384 + 32768;
#pragma unroll
  for (int e = 0; e < 2; ++e) {
    const int idx = g + e * 8192;  // 0..16383
    const int b = idx >> 8, o = idx & 255;
    const float* hr = hT1 + (b << 9);
    const float* wr = outW + (o << 9);
    float s0 = 0.f, s1 = 0.f;
    for (int k = 0; k < 512; k += 8) {
      float4 h4 = *(const float4*)(hr + k);
      float4 w4 = *(const float4*)(wr + k);
      s0 += h4.x * w4.x + h4.y * w4.y + h4.z * w4.z + h4.w * w4.w;
      float4 h5 = *(const float4*)(hr + k + 4);
      float4 w5 = *(const float4*)(wr + k + 4);
      s1 += h5.x * w5.x + h5.y * w5.y + h5.z * w5.z + h5.w * w5.w;
    }
    out[idx] = s0 + s1 + outb[o];
  }
}

extern "C" void kernel_launch(void* const* d_in, const int* in_sizes, int n_in,
                              void* d_out, int out_size, void* d_ws, size_t ws_size,
                              hipStream_t stream) {
  const float* x = (const float*)d_in[0];
  const float* inW = (const float*)d_in[1];
  const float* inb = (const float*)d_in[2];
  const float* i2h = (const float*)d_in[3];
  const float* h2h = (const float*)d_in[4];
  const float* hbias = (const float*)d_in[5];
  const float* outW = (const float*)d_in[6];
  const float* outb = (const float*)d_in[7];
  float* out = (float*)d_out;

  char* w = (char*)d_ws;
  unsigned short* WiB = (unsigned short*)w;                              // 1 MB
  unsigned short* WhB = (unsigned short*)(w + (1u << 20));               // 1 MB
  unsigned short* WinB = (unsigned short*)(w + (2u << 20));              // 256 KB
  unsigned short* h0 = (unsigned short*)(w + (2u << 20) + (256u << 10)); // 128 KB
  unsigned short* h1 = (unsigned short*)(w + (2u << 20) + (384u << 10)); // 128 KB
  unsigned* bar = (unsigned*)(w + (2u << 20) + (512u << 10));            // pad 1 KB
  unsigned short* xeB = (unsigned short*)(w + (2u << 20) + (512u << 10) + 1024);  // 32 MB

  prep_kernel<<<2048, 256, 0, stream>>>(inW, i2h, h2h, WinB, WiB, WhB, h0, h1, bar);
  proj_kernel<<<16384, 256, 0, stream>>>(x, WinB, inb, xeB);
  scan_kernel<<<NWG, 256, 0, stream>>>(xeB, WiB, WhB, hbias, outW, outb, h0, h1, out, bar);
}

// Round 3
// 3702.015 us; speedup vs baseline: 1.9895x; 1.8870x over previous
//
#include <hip/hip_runtime.h>

typedef __attribute__((ext_vector_type(8))) short bf16x8;
typedef __attribute__((ext_vector_type(4))) float f32x4;

#define NWG 32

__device__ __forceinline__ unsigned short f2bf(float f) {
  union { float f; unsigned u; } v; v.f = f;
  unsigned r = v.u + 0x7FFFu + ((v.u >> 16) & 1u);
  return (unsigned short)(r >> 16);
}

__device__ __forceinline__ float bf2f(unsigned short u) {
  union { unsigned u; float f; } v; v.u = (unsigned)u << 16;
  return v.f;
}

__device__ __forceinline__ float fast_tanh(float x) {
  float ax = fminf(fabsf(x), 15.f);
  float e = __expf(2.f * ax);
  float t = (e - 1.f) / (e + 1.f);
  return copysignf(t, x);
}

// Batched L3-coherent 16B load: plain global_load with device-coherence bits
// (sc0 sc1) -> bypasses non-coherent L2, serviced at the coherence point.
// Issued WITHOUT an implicit wait so 32 of them pipeline; one explicit
// s_waitcnt vmcnt(0) + empty-asm guards order the uses.
#define LDH(d, b, O) \
  asm volatile("global_load_dwordx4 %0, %1, off offset:" #O " sc0 sc1" : "=v"(d) : "v"(b))
#define LDH16(A, B)            \
  LDH(A[0], B, 0);   LDH(A[1], B, 64);  LDH(A[2], B, 128); LDH(A[3], B, 192);  \
  LDH(A[4], B, 256); LDH(A[5], B, 320); LDH(A[6], B, 384); LDH(A[7], B, 448);  \
  LDH(A[8], B, 512); LDH(A[9], B, 576); LDH(A[10], B, 640); LDH(A[11], B, 704); \
  LDH(A[12], B, 768); LDH(A[13], B, 832); LDH(A[14], B, 896); LDH(A[15], B, 960)

// ---------- prep: fp32->bf16 recurrent weights, zero h state + barrier ----------
__global__ void prep_kernel(const float* __restrict__ i2h,
                            const float* __restrict__ h2h,
                            unsigned short* __restrict__ WiB,
                            unsigned short* __restrict__ WhB,
                            unsigned short* __restrict__ h0,
                            unsigned short* __restrict__ h1,
                            unsigned* __restrict__ bar) {
  int i = blockIdx.x * 256 + threadIdx.x;  // grid covers 524288 = L*H*H
  WiB[i] = f2bf(i2h[i]);
  WhB[i] = f2bf(h2h[i]);
  if (i < 65536) { h0[i] = 0; h1[i] = 0; }
  if (i < 64) bar[i] = 0;
}

// ---------- wc: Wc[n,i] = sum_k Wi0[n,k]*inW[k,i]; bc[n] = Wi0[n,:].inb + b0[n] ----------
__global__ __launch_bounds__(256) void wc_kernel(const float* __restrict__ inW,
                                                 const float* __restrict__ inb,
                                                 const float* __restrict__ i2h,
                                                 const float* __restrict__ hb,
                                                 unsigned short* __restrict__ WcB,
                                                 float* __restrict__ bc) {
  const int n = blockIdx.x, i = threadIdx.x;
  const float* wrow = i2h + (size_t)n * 512;
  float acc = 0.f;
  for (int k = 0; k < 512; ++k) acc += wrow[k] * inW[k * 256 + i];
  WcB[n * 256 + i] = f2bf(acc);
  if (i == 0) {
    float a2 = 0.f;
    for (int k = 0; k < 512; ++k) a2 += wrow[k] * inb[k];
    bc[n] = a2 + hb[n];
  }
}

// ---------- proj: U[s][b][n] = x[b,s,:] . Wc[n,:] + bc[n]  (bf16 out) ----------
__global__ __launch_bounds__(256) void proj_kernel(const float* __restrict__ x,
                                                   const unsigned short* __restrict__ WcB,
                                                   const float* __restrict__ bc,
                                                   unsigned short* __restrict__ U) {
  const int tid = threadIdx.x;
  const int ln = tid & 63, wv = tid >> 6;
  const int wid = blockIdx.x * 4 + wv;  // 0..65535 ; M-tiles 2048 x N-tiles 32
  const int mt = wid >> 5, nt = wid & 31;
  const int mrow = ln & 15, quad = ln >> 4, koff = quad * 8;
  const float* arow = x + (size_t)(mt * 16 + mrow) * 256 + koff;   // m = b*512+s
  const unsigned short* brow = WcB + (size_t)(nt * 16 + mrow) * 256 + koff;
  f32x4 acc = {0.f, 0.f, 0.f, 0.f};
#pragma unroll
  for (int kk = 0; kk < 8; ++kk) {
    const int ko = kk * 32;
    bf16x8 af;
#pragma unroll
    for (int j = 0; j < 8; ++j) af[j] = (short)f2bf(arow[ko + j]);
    bf16x8 bf = *(const bf16x8*)(brow + ko);
    acc = __builtin_amdgcn_mfma_f32_16x16x32_bf16(af, bf, acc, 0, 0, 0);
  }
  const int n = nt * 16 + mrow;
  const float bias = bc[n];
  const int m0 = mt * 16 + quad * 4;
#pragma unroll
  for (int r = 0; r < 4; ++r) {
    const int m = m0 + r;
    const int b = m >> 9, s = m & 511;
    U[((size_t)(s * 64 + b) << 9) + n] = f2bf(acc[r] + bias);
  }
}

// ---------- grid barrier (light: no L2 maintenance; heavy: full fences once) ----------
template <bool FENCE>
__device__ __forceinline__ void grid_barrier(unsigned* bar, unsigned epoch) {
  __builtin_amdgcn_s_waitcnt(0);  // drain own sc1 stores to coherence point
  __syncthreads();
  if (threadIdx.x == 0) {
    if (FENCE) __threadfence();
    unsigned prev = __hip_atomic_fetch_add(bar, 1u, __ATOMIC_RELAXED, __HIP_MEMORY_SCOPE_AGENT);
    if (prev == epoch * NWG + (NWG - 1)) {
      __hip_atomic_store(bar + 32, epoch + 1u, __ATOMIC_RELAXED, __HIP_MEMORY_SCOPE_AGENT);
    } else {
      while (__hip_atomic_load(bar + 32, __ATOMIC_RELAXED, __HIP_MEMORY_SCOPE_AGENT) < epoch + 1u)
        __builtin_amdgcn_s_sleep(1);
    }
    if (FENCE) __threadfence();
  }
  __syncthreads();
}

// Pack lane's 4 outputs with column-neighbor via shfl_xor -> two sc1 dword stores.
__device__ __forceinline__ void store_h_coh(unsigned* dbase, int rowbase, int colp,
                                            bool evenl,
                                            float v0, float v1, float v2, float v3) {
  unsigned lo = (unsigned)f2bf(v0) | ((unsigned)f2bf(v1) << 16);
  unsigned hi = (unsigned)f2bf(v2) | ((unsigned)f2bf(v3) << 16);
  unsigned send = evenl ? hi : lo;
  unsigned recv = __shfl_xor(send, 1, 64);
  unsigned w0, w1; int rb;
  if (evenl) {
    w0 = (lo & 0xffffu) | (recv << 16);
    w1 = (lo >> 16) | (recv & 0xffff0000u);
    rb = rowbase;
  } else {
    w0 = (recv & 0xffffu) | (hi << 16);
    w1 = (recv >> 16) | (hi & 0xffff0000u);
    rb = rowbase + 2;
  }
  unsigned* p = dbase + rb * 256 + colp;
  __hip_atomic_store(p, w0, __ATOMIC_RELAXED, __HIP_MEMORY_SCOPE_AGENT);
  __hip_atomic_store(p + 256, w1, __ATOMIC_RELAXED, __HIP_MEMORY_SCOPE_AGENT);
}

__global__ __launch_bounds__(256, 1) void scan_kernel(const unsigned short* __restrict__ U,
                                                      const unsigned short* __restrict__ WiB,
                                                      const unsigned short* __restrict__ WhB,
                                                      const float* __restrict__ hb,
                                                      const float* __restrict__ outW,
                                                      const float* __restrict__ outb,
                                                      unsigned short* __restrict__ h0,
                                                      unsigned short* __restrict__ h1,
                                                      float* __restrict__ out,
                                                      unsigned* __restrict__ bar) {
  const int tid = threadIdx.x;
  const int ln = tid & 63, wv = tid >> 6;
  const int mrow = ln & 15, quad = ln >> 4, koff = quad * 8;
  const int rt = wv;                 // batch tile 0..3 (4 waves/WG cover all 64 batches)
  const int ct = blockIdx.x;         // column tile 0..31
  const int bA = rt * 16 + mrow;     // A fragment row = batch index
  const int n = ct * 16 + mrow;      // B fragment / output column
  const bool evenl = (ln & 1) == 0;
  const int colp = n >> 1;
  const int rowbase = rt * 16 + quad * 4;

  // register/AGPR-resident weights: rows n of Wh0, Wi1, Wh1 (48 frags = 192 regs)
  bf16x8 wf0[16], wf1[16], wf2[16];
  {
    const unsigned short* w0 = WhB + (size_t)n * 512 + koff;                 // Wh0
    const unsigned short* w1 = WiB + (size_t)262144 + (size_t)n * 512 + koff; // Wi1
    const unsigned short* w2 = WhB + (size_t)262144 + (size_t)n * 512 + koff; // Wh1
#pragma unroll
    for (int kk = 0; kk < 16; ++kk) {
      wf0[kk] = *(const bf16x8*)(w0 + kk * 32);
      wf1[kk] = *(const bf16x8*)(w1 + kk * 32);
      wf2[kk] = *(const bf16x8*)(w2 + kk * 32);
    }
  }
  const float bias1 = hb[512 + n];
  const unsigned short* h0b = h0 + (size_t)bA * 512 + koff;
  const unsigned short* h1b = h1 + (size_t)bA * 512 + koff;
  const unsigned short* UB = U + ((size_t)rowbase << 9) + n;

  // U(0) preload (rows rowbase..rowbase+3, col n)
  unsigned short up0 = UB[0], up1 = UB[512], up2 = UB[1024], up3 = UB[1536];

  // stage s: layer0 at t=s (s<512), layer1 at t=s-1 (s>=1). 513 stages/barriers.
  for (int s = 0; s <= 512; ++s) {
    const int pd = s & 1, ps = pd ^ 1;
    const unsigned short* aH0 = h0b + (ps << 15);  // h0(s-1): L0.h2h == L1.i2h input
    const unsigned short* aH1 = h1b + (pd << 15);  // h1(s-2) for L1.h2h

    // ---- batched coherent loads: issue all 32, single wait ----
    bf16x8 h0f[16], h1f[16];
    LDH16(h0f, aH0);
    LDH16(h1f, aH1);
    asm volatile("s_waitcnt vmcnt(0)" ::: "memory");
#pragma unroll
    for (int kk = 0; kk < 16; ++kk) {
      asm volatile("" : "+v"(h0f[kk]));
      asm volatile("" : "+v"(h1f[kk]));
    }

    f32x4 z = {0.f, 0.f, 0.f, 0.f};
    f32x4 acc0 = z, a1a = z, a1b = z;
    const bool D0 = (s < 512), D1 = (s > 0);
#pragma unroll
    for (int kk = 0; kk < 16; ++kk) {
      if (D0) acc0 = __builtin_amdgcn_mfma_f32_16x16x32_bf16(h0f[kk], wf0[kk], acc0, 0, 0, 0);
      if (D1) {
        a1a = __builtin_amdgcn_mfma_f32_16x16x32_bf16(h0f[kk], wf1[kk], a1a, 0, 0, 0);
        a1b = __builtin_amdgcn_mfma_f32_16x16x32_bf16(h1f[kk], wf2[kk], a1b, 0, 0, 0);
      }
    }

    // ---- prefetch U(s+1): normal loads in flight across the barrier ----
    unsigned short un0 = 0, un1 = 0, un2 = 0, un3 = 0;
    if (s <= 510) {
      const unsigned short* un = UB + ((size_t)(s + 1) << 15);
      un0 = un[0]; un1 = un[512]; un2 = un[1024]; un3 = un[1536];
    }

    if (D0) {  // layer0 output at t=s -> h0[pd]; U folds in Wi0-part + biases
      float v0 = fast_tanh(acc0[0] + bf2f(up0));
      float v1 = fast_tanh(acc0[1] + bf2f(up1));
      float v2 = fast_tanh(acc0[2] + bf2f(up2));
      float v3 = fast_tanh(acc0[3] + bf2f(up3));
      store_h_coh((unsigned*)h0 + (pd << 14), rowbase, colp, evenl, v0, v1, v2, v3);
      if (s == 511) {
        float* o = out + 16384 + rowbase * 512 + n;  // hT[0]
        o[0] = v0; o[512] = v1; o[1024] = v2; o[1536] = v3;
      }
    }
    if (D1) {  // layer1 output at t=s-1 -> h1[ps]
      float v0 = fast_tanh(a1a[0] + a1b[0] + bias1);
      float v1 = fast_tanh(a1a[1] + a1b[1] + bias1);
      float v2 = fast_tanh(a1a[2] + a1b[2] + bias1);
      float v3 = fast_tanh(a1a[3] + a1b[3] + bias1);
      store_h_coh((unsigned*)h1 + (ps << 14), rowbase, colp, evenl, v0, v1, v2, v3);
      if (s == 512) {
        float* o = out + 16384 + 32768 + rowbase * 512 + n;  // hT[1]
        o[0] = v0; o[512] = v1; o[1024] = v2; o[1536] = v3;
      }
    }
    up0 = un0; up1 = un1; up2 = un2; up3 = un3;

    if (s == 512) grid_barrier<true>(bar, (unsigned)s);   // heavy: flush hT fp32 stores
    else          grid_barrier<false>(bar, (unsigned)s);  // light
  }

  // output = hT[1] @ out_W.T + out_b
  const int g = blockIdx.x * 256 + tid;  // 0..8191
  const float* hT1 = out + 16384 + 32768;
#pragma unroll
  for (int e = 0; e < 2; ++e) {
    const int idx = g + e * 8192;  // 0..16383
    const int b = idx >> 8, o = idx & 255;
    const float* hr = hT1 + (b << 9);
    const float* wr = outW + (o << 9);
    float s0 = 0.f, s1 = 0.f;
    for (int k = 0; k < 512; k += 8) {
      float4 h4 = *(const float4*)(hr + k);
      float4 w4 = *(const float4*)(wr + k);
      s0 += h4.x * w4.x + h4.y * w4.y + h4.z * w4.z + h4.w * w4.w;
      float4 h5 = *(const float4*)(hr + k + 4);
      float4 w5 = *(const float4*)(wr + k + 4);
      s1 += h5.x * w5.x + h5.y * w5.y + h5.z * w5.z + h5.w * w5.w;
    }
    out[idx] = s0 + s1 + outb[o];
  }
}

extern "C" void kernel_launch(void* const* d_in, const int* in_sizes, int n_in,
                              void* d_out, int out_size, void* d_ws, size_t ws_size,
                              hipStream_t stream) {
  const float* x = (const float*)d_in[0];
  const float* inW = (const float*)d_in[1];
  const float* inb = (const float*)d_in[2];
  const float* i2h = (const float*)d_in[3];
  const float* h2h = (const float*)d_in[4];
  const float* hbias = (const float*)d_in[5];
  const float* outW = (const float*)d_in[6];
  const float* outb = (const float*)d_in[7];
  float* out = (float*)d_out;

  char* w = (char*)d_ws;
  unsigned short* WiB = (unsigned short*)w;                               // 1 MB
  unsigned short* WhB = (unsigned short*)(w + (1u << 20));                // 1 MB
  unsigned short* WcB = (unsigned short*)(w + (2u << 20));                // 256 KB
  float* bc = (float*)(w + (2u << 20) + (256u << 10));                    // 4 KB
  unsigned short* h0 = (unsigned short*)(w + (2u << 20) + (260u << 10));  // 128 KB
  unsigned short* h1 = (unsigned short*)(w + (2u << 20) + (388u << 10));  // 128 KB
  unsigned* bar = (unsigned*)(w + (2u << 20) + (516u << 10));             // 4 KB
  unsigned short* U = (unsigned short*)(w + (2u << 20) + (576u << 10));   // 32 MB

  prep_kernel<<<2048, 256, 0, stream>>>(i2h, h2h, WiB, WhB, h0, h1, bar);
  wc_kernel<<<512, 256, 0, stream>>>(inW, inb, i2h, hbias, WcB, bc);
  proj_kernel<<<16384, 256, 0, stream>>>(x, WcB, bc, U);
  scan_kernel<<<NWG, 256, 0, stream>>>(U, WiB, WhB, hbias, outW, outb, h0, h1, out, bar);
}

// Round 4
// 2100.350 us; speedup vs baseline: 3.5066x; 1.7626x over previous
//
#include <hip/hip_runtime.h>

typedef __attribute__((ext_vector_type(8))) short bf16x8;
typedef __attribute__((ext_vector_type(4))) float f32x4;

#define NWG 128  // 128 single-wave workgroups (1 wave/CU)

__device__ __forceinline__ unsigned short f2bf(float f) {
  union { float f; unsigned u; } v; v.f = f;
  unsigned r = v.u + 0x7FFFu + ((v.u >> 16) & 1u);
  return (unsigned short)(r >> 16);
}

__device__ __forceinline__ float bf2f(unsigned short u) {
  union { unsigned u; float f; } v; v.u = (unsigned)u << 16;
  return v.f;
}

__device__ __forceinline__ float fast_tanh(float x) {
  float ax = fminf(fabsf(x), 15.f);
  float e = __expf(2.f * ax);
  float t = (e - 1.f) / (e + 1.f);
  return copysignf(t, x);
}

// Batched L3-coherent 16B load (sc0 sc1 -> bypass L1/L2, serviced at coherence
// point). Issued without implicit wait so 32 pipeline; one s_waitcnt after.
#define LDH(d, b, O) \
  asm volatile("global_load_dwordx4 %0, %1, off offset:" #O " sc0 sc1" : "=v"(d) : "v"(b))
#define LDH16(A, B)            \
  LDH(A[0], B, 0);   LDH(A[1], B, 64);  LDH(A[2], B, 128); LDH(A[3], B, 192);  \
  LDH(A[4], B, 256); LDH(A[5], B, 320); LDH(A[6], B, 384); LDH(A[7], B, 448);  \
  LDH(A[8], B, 512); LDH(A[9], B, 576); LDH(A[10], B, 640); LDH(A[11], B, 704); \
  LDH(A[12], B, 768); LDH(A[13], B, 832); LDH(A[14], B, 896); LDH(A[15], B, 960)

// Poll this rt-group's 32 per-wave flags (128B-strided lines), lane-parallel.
__device__ __forceinline__ void wait_flags(const unsigned* p, unsigned tgt) {
  while (true) {
    unsigned v;
    asm volatile("global_load_dword %0, %1, off sc0 sc1\n\t"
                 "s_waitcnt vmcnt(0)"
                 : "=v"(v) : "v"(p) : "memory");
    if (__all((int)(v >= tgt))) break;
  }
}

// ---------- prep: fp32->bf16 recurrent weights, zero h state + flags + bar ----------
__global__ void prep_kernel(const float* __restrict__ i2h,
                            const float* __restrict__ h2h,
                            unsigned short* __restrict__ WiB,
                            unsigned short* __restrict__ WhB,
                            unsigned short* __restrict__ h0,
                            unsigned short* __restrict__ h1,
                            unsigned* __restrict__ bar,
                            unsigned* __restrict__ flags) {
  int i = blockIdx.x * 256 + threadIdx.x;  // grid covers 524288 = L*H*H
  WiB[i] = f2bf(i2h[i]);
  WhB[i] = f2bf(h2h[i]);
  if (i < 65536) { h0[i] = 0; h1[i] = 0; }
  if (i < 64) bar[i] = 0;
  if (i < 4096) flags[i] = 0;
}

// ---------- wc: Wc[n,i] = sum_k Wi0[n,k]*inW[k,i]; bc[n] = Wi0[n,:].inb + b0[n] ----------
__global__ __launch_bounds__(256) void wc_kernel(const float* __restrict__ inW,
                                                 const float* __restrict__ inb,
                                                 const float* __restrict__ i2h,
                                                 const float* __restrict__ hb,
                                                 unsigned short* __restrict__ WcB,
                                                 float* __restrict__ bc) {
  const int n = blockIdx.x, i = threadIdx.x;
  const float* wrow = i2h + (size_t)n * 512;
  float acc = 0.f;
  for (int k = 0; k < 512; ++k) acc += wrow[k] * inW[k * 256 + i];
  WcB[n * 256 + i] = f2bf(acc);
  if (i == 0) {
    float a2 = 0.f;
    for (int k = 0; k < 512; ++k) a2 += wrow[k] * inb[k];
    bc[n] = a2 + hb[n];
  }
}

// ---------- proj: U[s][b][n] = x[b,s,:] . Wc[n,:] + bc[n]  (bf16 out) ----------
__global__ __launch_bounds__(256) void proj_kernel(const float* __restrict__ x,
                                                   const unsigned short* __restrict__ WcB,
                                                   const float* __restrict__ bc,
                                                   unsigned short* __restrict__ U) {
  const int tid = threadIdx.x;
  const int ln = tid & 63, wv = tid >> 6;
  const int wid = blockIdx.x * 4 + wv;  // 0..65535 ; M-tiles 2048 x N-tiles 32
  const int mt = wid >> 5, nt = wid & 31;
  const int mrow = ln & 15, quad = ln >> 4, koff = quad * 8;
  const float* arow = x + (size_t)(mt * 16 + mrow) * 256 + koff;   // m = b*512+s
  const unsigned short* brow = WcB + (size_t)(nt * 16 + mrow) * 256 + koff;
  f32x4 acc = {0.f, 0.f, 0.f, 0.f};
#pragma unroll
  for (int kk = 0; kk < 8; ++kk) {
    const int ko = kk * 32;
    bf16x8 af;
#pragma unroll
    for (int j = 0; j < 8; ++j) af[j] = (short)f2bf(arow[ko + j]);
    bf16x8 bf = *(const bf16x8*)(brow + ko);
    acc = __builtin_amdgcn_mfma_f32_16x16x32_bf16(af, bf, acc, 0, 0, 0);
  }
  const int n = nt * 16 + mrow;
  const float bias = bc[n];
  const int m0 = mt * 16 + quad * 4;
#pragma unroll
  for (int r = 0; r < 4; ++r) {
    const int m = m0 + r;
    const int b = m >> 9, s = m & 511;
    U[((size_t)(s * 64 + b) << 9) + n] = f2bf(acc[r] + bias);
  }
}

// ---------- heavy grid barrier (once, before epilogue): full fence protocol ----------
__device__ __forceinline__ void heavy_barrier(unsigned* bar) {
  __builtin_amdgcn_s_waitcnt(0);
  __syncthreads();
  if (threadIdx.x == 0) {
    __threadfence();  // release: wbl2 (flush dirty hT lines cross-XCD)
    unsigned prev = __hip_atomic_fetch_add(bar, 1u, __ATOMIC_RELAXED, __HIP_MEMORY_SCOPE_AGENT);
    if (prev == NWG - 1) {
      __hip_atomic_store(bar + 32, 1u, __ATOMIC_RELAXED, __HIP_MEMORY_SCOPE_AGENT);
    } else {
      while (__hip_atomic_load(bar + 32, __ATOMIC_RELAXED, __HIP_MEMORY_SCOPE_AGENT) < 1u)
        __builtin_amdgcn_s_sleep(1);
    }
    __threadfence();  // acquire: inv (drop stale L1/L2 before epilogue reads)
  }
  __syncthreads();
}

// Pack lane's 4 outputs with column-neighbor via shfl_xor -> two sc1 dword stores.
__device__ __forceinline__ void store_h_coh(unsigned* dbase, int rowbase, int colp,
                                            bool evenl,
                                            float v0, float v1, float v2, float v3) {
  unsigned lo = (unsigned)f2bf(v0) | ((unsigned)f2bf(v1) << 16);
  unsigned hi = (unsigned)f2bf(v2) | ((unsigned)f2bf(v3) << 16);
  unsigned send = evenl ? hi : lo;
  unsigned recv = __shfl_xor(send, 1, 64);
  unsigned w0, w1; int rb;
  if (evenl) {
    w0 = (lo & 0xffffu) | (recv << 16);
    w1 = (lo >> 16) | (recv & 0xffff0000u);
    rb = rowbase;
  } else {
    w0 = (recv & 0xffffu) | (hi << 16);
    w1 = (recv >> 16) | (hi & 0xffff0000u);
    rb = rowbase + 2;
  }
  unsigned* p = dbase + rb * 256 + colp;
  __hip_atomic_store(p, w0, __ATOMIC_RELAXED, __HIP_MEMORY_SCOPE_AGENT);
  __hip_atomic_store(p + 256, w1, __ATOMIC_RELAXED, __HIP_MEMORY_SCOPE_AGENT);
}

__global__ __launch_bounds__(64, 1) void scan_kernel(const unsigned short* __restrict__ U,
                                                     const unsigned short* __restrict__ WiB,
                                                     const unsigned short* __restrict__ WhB,
                                                     const float* __restrict__ hb,
                                                     const float* __restrict__ outW,
                                                     const float* __restrict__ outb,
                                                     unsigned short* __restrict__ h0,
                                                     unsigned short* __restrict__ h1,
                                                     float* __restrict__ out,
                                                     unsigned* __restrict__ bar,
                                                     unsigned* __restrict__ flags) {
  const int ln = threadIdx.x;          // single wave per WG
  const int wid = blockIdx.x;          // 0..127
  const int rt = wid & 3;              // batch tile (sync domain)
  const int ct = wid >> 2;             // column tile 0..31
  const int mrow = ln & 15, quad = ln >> 4, koff = quad * 8;
  const int bA = rt * 16 + mrow;       // A fragment row = batch index
  const int n = ct * 16 + mrow;        // B fragment / output column
  const bool evenl = (ln & 1) == 0;
  const int colp = n >> 1;
  const int rowbase = rt * 16 + quad * 4;

  // register/AGPR-resident weights: rows n of Wh0, Wi1, Wh1 (48 frags)
  bf16x8 wf0[16], wf1[16], wf2[16];
  {
    const unsigned short* w0 = WhB + (size_t)n * 512 + koff;                  // Wh0
    const unsigned short* w1 = WiB + (size_t)262144 + (size_t)n * 512 + koff; // Wi1
    const unsigned short* w2 = WhB + (size_t)262144 + (size_t)n * 512 + koff; // Wh1
#pragma unroll
    for (int kk = 0; kk < 16; ++kk) {
      wf0[kk] = *(const bf16x8*)(w0 + kk * 32);
      wf1[kk] = *(const bf16x8*)(w1 + kk * 32);
      wf2[kk] = *(const bf16x8*)(w2 + kk * 32);
    }
  }
  const float bias1 = hb[512 + n];
  const unsigned short* h0b = h0 + (size_t)bA * 512 + koff;
  const unsigned short* h1b = h1 + (size_t)bA * 512 + koff;
  const unsigned short* UB = U + ((size_t)rowbase << 9) + n;
  unsigned* myflag = flags + ((rt * 32 + ct) << 5);                 // own line
  const unsigned* pollp = flags + ((rt * 32 + (ln & 31)) << 5);     // lane-parallel

  // U(0) preload (rows rowbase..+3, col n)
  unsigned short up0 = UB[0], up1 = UB[512], up2 = UB[1024], up3 = UB[1536];

  // stage s: layer0 at t=s (s<512), layer1 at t=s-1 (s>=1). 513 stages.
  for (int s = 0; s <= 512; ++s) {
    const int pd = s & 1, ps = pd ^ 1;
    if (s) wait_flags(pollp, (unsigned)s);  // peers finished stage s-1 (stores drained)

    const unsigned short* aH0 = h0b + (ps << 15);  // h0(s-1): L0.h2h == L1.i2h input
    const unsigned short* aH1 = h1b + (pd << 15);  // h1(s-2) for L1.h2h
    bf16x8 h0f[16], h1f[16];
    LDH16(h0f, aH0);
    LDH16(h1f, aH1);
    asm volatile("s_waitcnt vmcnt(0)" ::: "memory");
#pragma unroll
    for (int kk = 0; kk < 16; ++kk) {
      asm volatile("" : "+v"(h0f[kk]));
      asm volatile("" : "+v"(h1f[kk]));
    }

    f32x4 z = {0.f, 0.f, 0.f, 0.f};
    f32x4 acc0 = z, a1a = z, a1b = z;
    const bool D0 = (s < 512), D1 = (s > 0);
#pragma unroll
    for (int kk = 0; kk < 16; ++kk) {
      if (D0) acc0 = __builtin_amdgcn_mfma_f32_16x16x32_bf16(h0f[kk], wf0[kk], acc0, 0, 0, 0);
      if (D1) {
        a1a = __builtin_amdgcn_mfma_f32_16x16x32_bf16(h0f[kk], wf1[kk], a1a, 0, 0, 0);
        a1b = __builtin_amdgcn_mfma_f32_16x16x32_bf16(h1f[kk], wf2[kk], a1b, 0, 0, 0);
      }
    }

    if (D0) {  // layer0 output at t=s -> h0[pd]; U carries Wc-part + biases
      float v0 = fast_tanh(acc0[0] + bf2f(up0));
      float v1 = fast_tanh(acc0[1] + bf2f(up1));
      float v2 = fast_tanh(acc0[2] + bf2f(up2));
      float v3 = fast_tanh(acc0[3] + bf2f(up3));
      store_h_coh((unsigned*)h0 + (pd << 14), rowbase, colp, evenl, v0, v1, v2, v3);
      if (s == 511) {
        float* o = out + 16384 + rowbase * 512 + n;  // hT[0]
        o[0] = v0; o[512] = v1; o[1024] = v2; o[1536] = v3;
      }
    }
    if (D1) {  // layer1 output at t=s-1 -> h1[ps]
      float v0 = fast_tanh(a1a[0] + a1b[0] + bias1);
      float v1 = fast_tanh(a1a[1] + a1b[1] + bias1);
      float v2 = fast_tanh(a1a[2] + a1b[2] + bias1);
      float v3 = fast_tanh(a1a[3] + a1b[3] + bias1);
      store_h_coh((unsigned*)h1 + (ps << 14), rowbase, colp, evenl, v0, v1, v2, v3);
      if (s == 512) {
        float* o = out + 16384 + 32768 + rowbase * 512 + n;  // hT[1]
        o[0] = v0; o[512] = v1; o[1024] = v2; o[1536] = v3;
      }
    }

    // drain h stores, then publish flag (plain sc1 store, no RMW, no broadcast)
    asm volatile("s_waitcnt vmcnt(0)" ::: "memory");
    if (ln == 0) {
      unsigned fv = (unsigned)(s + 1);
      asm volatile("global_store_dword %0, %1, off sc0 sc1" :: "v"(myflag), "v"(fv) : "memory");
    }

    // U(s+1) prefetch AFTER flag store: off the flag-propagation critical path
    if (s <= 510) {
      const unsigned short* un = UB + ((size_t)(s + 1) << 15);
      up0 = un[0]; up1 = un[512]; up2 = un[1024]; up3 = un[1536];
    }
  }

  heavy_barrier(bar);

  // output = hT[1] @ out_W.T + out_b
  const int g = blockIdx.x * 64 + ln;  // 0..8191
  const float* hT1 = out + 16384 + 32768;
#pragma unroll
  for (int e = 0; e < 2; ++e) {
    const int idx = g + e * 8192;  // 0..16383
    const int b = idx >> 8, o = idx & 255;
    const float* hr = hT1 + (b << 9);
    const float* wr = outW + (o << 9);
    float s0 = 0.f, s1 = 0.f;
    for (int k = 0; k < 512; k += 8) {
      float4 h4 = *(const float4*)(hr + k);
      float4 w4 = *(const float4*)(wr + k);
      s0 += h4.x * w4.x + h4.y * w4.y + h4.z * w4.z + h4.w * w4.w;
      float4 h5 = *(const float4*)(hr + k + 4);
      float4 w5 = *(const float4*)(wr + k + 4);
      s1 += h5.x * w5.x + h5.y * w5.y + h5.z * w5.z + h5.w * w5.w;
    }
    out[idx] = s0 + s1 + outb[o];
  }
}

extern "C" void kernel_launch(void* const* d_in, const int* in_sizes, int n_in,
                              void* d_out, int out_size, void* d_ws, size_t ws_size,
                              hipStream_t stream) {
  const float* x = (const float*)d_in[0];
  const float* inW = (const float*)d_in[1];
  const float* inb = (const float*)d_in[2];
  const float* i2h = (const float*)d_in[3];
  const float* h2h = (const float*)d_in[4];
  const float* hbias = (const float*)d_in[5];
  const float* outW = (const float*)d_in[6];
  const float* outb = (const float*)d_in[7];
  float* out = (float*)d_out;

  char* w = (char*)d_ws;
  unsigned short* WiB = (unsigned short*)w;                               // 1 MB
  unsigned short* WhB = (unsigned short*)(w + (1u << 20));                // 1 MB
  unsigned short* WcB = (unsigned short*)(w + (2u << 20));                // 256 KB
  float* bc = (float*)(w + (2u << 20) + (256u << 10));                    // 4 KB
  unsigned short* h0 = (unsigned short*)(w + (2u << 20) + (260u << 10));  // 128 KB
  unsigned short* h1 = (unsigned short*)(w + (2u << 20) + (388u << 10));  // 128 KB
  unsigned* bar = (unsigned*)(w + (2u << 20) + (516u << 10));             // 4 KB
  unsigned* flags = (unsigned*)(w + (2u << 20) + (520u << 10));           // 16 KB
  unsigned short* U = (unsigned short*)(w + (2u << 20) + (576u << 10));   // 32 MB

  prep_kernel<<<2048, 256, 0, stream>>>(i2h, h2h, WiB, WhB, h0, h1, bar, flags);
  wc_kernel<<<512, 256, 0, stream>>>(inW, inb, i2h, hbias, WcB, bc);
  proj_kernel<<<16384, 256, 0, stream>>>(x, WcB, bc, U);
  scan_kernel<<<NWG, 64, 0, stream>>>(U, WiB, WhB, hbias, outW, outb, h0, h1, out, bar, flags);
}